// Round 5
// baseline (1174.329 us; speedup 1.0000x reference)
//
#include <hip/hip_runtime.h>
#include <hip/hip_bf16.h>

#define NND 100000
#define NED 1200000
#define NHOP 3
#define DM 64
#define EPSV 1e-5f
#define NB1 391   // ceil(NND/256)

typedef long long i64;
typedef unsigned short u16;
typedef unsigned int u32;

__device__ __forceinline__ float rlf(float v, int k) {
    return __builtin_bit_cast(float, __builtin_amdgcn_readlane(__builtin_bit_cast(int, v), k));
}
__device__ __forceinline__ float bf2f(u16 b) {
    return __builtin_bit_cast(float, (u32)b << 16);
}
__device__ __forceinline__ u16 f2bf(float f) {
    u32 u = __builtin_bit_cast(u32, f);
    return (u16)((u + 0x7FFFu + ((u >> 16) & 1u)) >> 16);
}
__device__ __forceinline__ float lo_f(u32 w) { return __builtin_bit_cast(float, w << 16); }
__device__ __forceinline__ float hi_f(u32 w) { return __builtin_bit_cast(float, w & 0xFFFF0000u); }

// --- xw = (softmax(comb_w[j]) . bb[1..3]) @ W -> bf16; optional rowptr-scale; optional stats ---
__global__ __launch_bounds__(256) void k_gemm(const float* __restrict__ bb,
                                              const float* __restrict__ comb_w, int j,
                                              const float* __restrict__ W,
                                              const int* __restrict__ rowptr, int scale,
                                              float* __restrict__ stats, int dostats,
                                              u16* __restrict__ xw) {
    const int lane = threadIdx.x & 63;
    float Wcol[DM];
#pragma unroll
    for (int k = 0; k < DM; k++) Wcol[k] = W[k * DM + lane];
    float c0 = comb_w[j * 3 + 0], c1 = comb_w[j * 3 + 1], c2 = comb_w[j * 3 + 2];
    float mx = fmaxf(c0, fmaxf(c1, c2));
    float e0 = expf(c0 - mx), e1 = expf(c1 - mx), e2 = expf(c2 - mx);
    float es = 1.0f / (e0 + e1 + e2);
    const float w0 = e0 * es, w1 = e1 * es, w2 = e2 * es;
    const float* b1 = bb + (i64)1 * NND * DM;
    const float* b2 = bb + (i64)2 * NND * DM;
    const float* b3 = bb + (i64)3 * NND * DM;
    int wave = (int)((blockIdx.x * blockDim.x + threadIdx.x) >> 6);
    int nw = (int)((gridDim.x * blockDim.x) >> 6);
    float s = 0.f, sq = 0.f;
    for (int n = wave; n < NND; n += nw) {
        i64 base = (i64)n * DM + lane;
        float m = w0 * b1[base] + w1 * b2[base] + w2 * b3[base];
        float a0 = 0.f, a1 = 0.f, a2 = 0.f, a3 = 0.f;
#pragma unroll
        for (int k = 0; k < DM; k += 4) {
            a0 = fmaf(rlf(m, k + 0), Wcol[k + 0], a0);
            a1 = fmaf(rlf(m, k + 1), Wcol[k + 1], a1);
            a2 = fmaf(rlf(m, k + 2), Wcol[k + 2], a2);
            a3 = fmaf(rlf(m, k + 3), Wcol[k + 3], a3);
        }
        float r = (a0 + a1) + (a2 + a3);
        if (scale) {
            int rs = rowptr[n], re = rowptr[n + 1];
            r *= rsqrtf((float)(re - rs) + 1.0f);
        }
        xw[base] = f2bf(r);
        s += r; sq += r * r;
    }
    if (dostats) {
        __shared__ float ls[4][DM], lq[4][DM];
        int row = threadIdx.x >> 6;
        ls[row][lane] = s; lq[row][lane] = sq;
        __syncthreads();
        if (row == 0) {
            s  = ls[0][lane] + ls[1][lane] + ls[2][lane] + ls[3][lane];
            sq = lq[0][lane] + lq[1][lane] + lq[2][lane] + lq[3][lane];
            unsafeAtomicAdd(&stats[lane], s);
            unsafeAtomicAdd(&stats[DM + lane], sq);
        }
    }
}

// --- in-degree histogram, all 3 hops in one pass ---
__global__ __launch_bounds__(256) void k_deg3(const int* __restrict__ edges, int* __restrict__ deg) {
    int i = blockIdx.x * blockDim.x + threadIdx.x;
    int stride = gridDim.x * blockDim.x;
    for (int e = i; e < NED; e += stride) {
#pragma unroll
        for (int h = 0; h < NHOP; h++) {
            int d = edges[(i64)h * 2 * NED + NED + e];   // dst of hop h
            atomicAdd(&deg[h * NND + d], 1);
        }
    }
}

// --- scan level 1 (batched over hops): block-local exclusive scan ---
__global__ __launch_bounds__(256) void k_scan1(const int* __restrict__ deg,
                                               int* __restrict__ loc,
                                               int* __restrict__ partials) {
    int t = threadIdx.x;
    int h = blockIdx.x / NB1;
    int lb = blockIdx.x - h * NB1;
    int n = lb * 256 + t;
    int d = (n < NND) ? deg[h * NND + n] : 0;
    __shared__ int sh[256];
    sh[t] = d;
    __syncthreads();
    for (int o = 1; o < 256; o <<= 1) {
        int v = (t >= o) ? sh[t - o] : 0;
        __syncthreads();
        sh[t] += v;
        __syncthreads();
    }
    if (n < NND) loc[h * NND + n] = sh[t] - d;
    if (t == 255) partials[h * 512 + lb] = sh[255];
}

// --- scan level 2: exclusive scan of block totals per hop ---
__global__ __launch_bounds__(512) void k_scan2(int* __restrict__ partials) {
    int t = threadIdx.x;
    int h = blockIdx.x;
    int d = (t < NB1) ? partials[h * 512 + t] : 0;
    __shared__ int sh[512];
    sh[t] = d;
    __syncthreads();
    for (int o = 1; o < 512; o <<= 1) {
        int v = (t >= o) ? sh[t - o] : 0;
        __syncthreads();
        sh[t] += v;
        __syncthreads();
    }
    if (t < NB1) partials[h * 512 + t] = sh[t] - d;
}

// --- finalize: rowptr (+sentinel) and cursor copy ---
__global__ __launch_bounds__(256) void k_fin(const int* __restrict__ loc,
                                             const int* __restrict__ partials,
                                             int* __restrict__ rowptr,
                                             int* __restrict__ cursor) {
    int i = blockIdx.x * blockDim.x + threadIdx.x;
    if (i >= NHOP * (NND + 1)) return;
    int h = i / (NND + 1);
    int n = i - h * (NND + 1);
    int v;
    if (n == NND) v = NED;
    else v = partials[h * 512 + (n >> 8)] + loc[h * NND + n];
    rowptr[h * (NND + 1) + n] = v;
    if (n < NND) cursor[h * NND + n] = v;
}

// --- bucket all 3 hops: sortedsrc grouped by dst ---
__global__ __launch_bounds__(256) void k_bucket3(const int* __restrict__ edges,
                                                 int* __restrict__ cursor,
                                                 int* __restrict__ sortedsrc) {
    int i = blockIdx.x * blockDim.x + threadIdx.x;
    int stride = gridDim.x * blockDim.x;
    for (int e = i; e < NED; e += stride) {
#pragma unroll
        for (int h = 0; h < NHOP; h++) {
            int s = edges[(i64)h * 2 * NED + e];
            int d = edges[(i64)h * 2 * NED + NED + e];
            int pos = atomicAdd(&cursor[h * NND + d], 1);
            sortedsrc[(i64)h * NED + pos] = s;
        }
    }
}

// --- gather: 8 edges per wave-load; x[n] = (sum xws[s] + xws[n]) * rsqrt(cnt+1); fused stats ---
__global__ __launch_bounds__(256) void k_gather(const u16* __restrict__ xws,
                                                const int* __restrict__ sorted,
                                                const int* __restrict__ rowptr,
                                                u16* __restrict__ xbuf,
                                                float* __restrict__ stats) {
    const int lane = threadIdx.x & 63;
    const int g = lane >> 3;   // edge slot 0..7
    const int c = lane & 7;    // feature chunk: features c*8 .. c*8+7
    const int wv = threadIdx.x >> 6;
    int wave = (int)((blockIdx.x * blockDim.x + threadIdx.x) >> 6);
    int nw = (int)((gridDim.x * blockDim.x) >> 6);
    float sA[8] = {0,0,0,0,0,0,0,0}, qA[8] = {0,0,0,0,0,0,0,0};
    for (int n = wave; n < NND; n += nw) {
        int start = rowptr[n];
        int cnt = rowptr[n + 1] - start;
        uint4 sv = *(const uint4*)(xws + (i64)n * DM + c * 8);   // self row chunk
        // self term must survive the 8-way group butterfly exactly once -> weight by (g==0)
        float selfw = (g == 0) ? 1.0f : 0.0f;
        float acc[8];
        acc[0] = lo_f(sv.x) * selfw; acc[1] = hi_f(sv.x) * selfw;
        acc[2] = lo_f(sv.y) * selfw; acc[3] = hi_f(sv.y) * selfw;
        acc[4] = lo_f(sv.z) * selfw; acc[5] = hi_f(sv.z) * selfw;
        acc[6] = lo_f(sv.w) * selfw; acc[7] = hi_f(sv.w) * selfw;
        int base = 0;
        while (base < cnt) {
            int take = cnt - base; if (take > 64) take = 64;
            int eidx = start + base + lane;
            if (eidx > NED - 1) eidx = NED - 1;
            int sli = sorted[eidx];
            int nr = (take + 7) >> 3;
            for (int r = 0; r < nr; r += 2) {
                int i0 = r * 8 + g;
                int i1 = i0 + 8;
                int s0 = __shfl(sli, i0);
                int s1 = __shfl(sli, i1 & 63);
                uint4 v0 = *(const uint4*)(xws + (i64)s0 * DM + c * 8);
                uint4 v1 = *(const uint4*)(xws + (i64)s1 * DM + c * 8);
                float m0 = (i0 < take) ? 1.0f : 0.0f;
                float m1 = (i1 < take) ? 1.0f : 0.0f;
                acc[0] = fmaf(lo_f(v0.x), m0, acc[0]); acc[1] = fmaf(hi_f(v0.x), m0, acc[1]);
                acc[2] = fmaf(lo_f(v0.y), m0, acc[2]); acc[3] = fmaf(hi_f(v0.y), m0, acc[3]);
                acc[4] = fmaf(lo_f(v0.z), m0, acc[4]); acc[5] = fmaf(hi_f(v0.z), m0, acc[5]);
                acc[6] = fmaf(lo_f(v0.w), m0, acc[6]); acc[7] = fmaf(hi_f(v0.w), m0, acc[7]);
                acc[0] = fmaf(lo_f(v1.x), m1, acc[0]); acc[1] = fmaf(hi_f(v1.x), m1, acc[1]);
                acc[2] = fmaf(lo_f(v1.y), m1, acc[2]); acc[3] = fmaf(hi_f(v1.y), m1, acc[3]);
                acc[4] = fmaf(lo_f(v1.z), m1, acc[4]); acc[5] = fmaf(hi_f(v1.z), m1, acc[5]);
                acc[6] = fmaf(lo_f(v1.w), m1, acc[6]); acc[7] = fmaf(hi_f(v1.w), m1, acc[7]);
            }
            base += take;
        }
        float dinv = rsqrtf((float)cnt + 1.0f);
#pragma unroll
        for (int i = 0; i < 8; i++) {
            float v = acc[i];
            v += __shfl_xor(v, 8);
            v += __shfl_xor(v, 16);
            v += __shfl_xor(v, 32);
            float x = v * dinv;
            acc[i] = x;
            sA[i] += x; qA[i] += x * x;
        }
        if (g == 0) {
            uint4 o;
            o.x = (u32)f2bf(acc[0]) | ((u32)f2bf(acc[1]) << 16);
            o.y = (u32)f2bf(acc[2]) | ((u32)f2bf(acc[3]) << 16);
            o.z = (u32)f2bf(acc[4]) | ((u32)f2bf(acc[5]) << 16);
            o.w = (u32)f2bf(acc[6]) | ((u32)f2bf(acc[7]) << 16);
            *(uint4*)(xbuf + (i64)n * DM + c * 8) = o;
        }
    }
    __shared__ float red[2][4][DM];
    if (g == 0) {
#pragma unroll
        for (int i = 0; i < 8; i++) {
            red[0][wv][c * 8 + i] = sA[i];
            red[1][wv][c * 8 + i] = qA[i];
        }
    }
    __syncthreads();
    if (threadIdx.x < DM) {
        int f = threadIdx.x;
        float s = red[0][0][f] + red[0][1][f] + red[0][2][f] + red[0][3][f];
        float q = red[1][0][f] + red[1][1][f] + red[1][2][f] + red[1][3][f];
        unsafeAtomicAdd(&stats[f], s);
        unsafeAtomicAdd(&stats[DM + f], q);
    }
}

// --- BN apply + accumulate; mode 0 folds ego BN; mode 2 adds log_softmax ---
__global__ __launch_bounds__(256) void k_apply(const u16* __restrict__ xbuf,
                                               const u16* __restrict__ xwsA, int mode,
                                               const float* __restrict__ statsA,
                                               const float* __restrict__ statsB,
                                               float* __restrict__ hidden,
                                               float* __restrict__ out) {
    const int lane = threadIdx.x & 63;
    float meanB = statsB[lane] * (1.0f / NND);
    float varB = statsB[DM + lane] * (1.0f / NND) - meanB * meanB;
    float invB = rsqrtf(varB + EPSV);
    float meanA = 0.f, invA = 0.f;
    if (mode == 0) {
        meanA = statsA[lane] * (1.0f / NND);
        float varA = statsA[DM + lane] * (1.0f / NND) - meanA * meanA;
        invA = rsqrtf(varA + EPSV);
    }
    int wave = (int)((blockIdx.x * blockDim.x + threadIdx.x) >> 6);
    int nw = (int)((gridDim.x * blockDim.x) >> 6);
    for (int n = wave; n < NND; n += nw) {
        i64 i = (i64)n * DM + lane;
        float bn = (bf2f(xbuf[i]) - meanB) * invB;
        float r = fmaxf(bn, 0.0f);
        if (mode == 0) {
            hidden[i] = (bf2f(xwsA[i]) - meanA) * invA + r;
        } else if (mode == 1) {
            hidden[i] += r;
        } else {
            float h = hidden[i] + r;
            float mx = h;
#pragma unroll
            for (int o = 32; o >= 1; o >>= 1) mx = fmaxf(mx, __shfl_xor(mx, o));
            float e = expf(h - mx);
            float ssum = e;
#pragma unroll
            for (int o = 32; o >= 1; o >>= 1) ssum += __shfl_xor(ssum, o);
            out[i] = h - mx - logf(ssum);
        }
    }
}

extern "C" void kernel_launch(void* const* d_in, const int* in_sizes, int n_in,
                              void* d_out, int out_size, void* d_ws, size_t ws_size,
                              hipStream_t stream) {
    const float* bb     = (const float*)d_in[0];
    const float* comb_w = (const float*)d_in[1];
    const float* ego_W  = (const float*)d_in[2];
    const float* conv_W = (const float*)d_in[4];
    const int*   edges  = (const int*)d_in[6];
    float* out = (float*)d_out;

    const i64 NF = (i64)NND * DM;
    char* ws = (char*)d_ws;
    float* stats     = (float*)ws;                      // 4*128 f
    u16*   xwsA      = (u16*)(ws + 4096);               // NF bf16 (ego)
    u16*   xwsB      = xwsA + NF;                       // NF bf16 (per-hop, reused)
    u16*   xbuf      = xwsB + NF;                       // NF bf16 (per-hop, reused)
    int*   deg       = (int*)(xbuf + NF);               // 3*NND
    int*   loc       = deg + 3 * NND;                   // 3*NND
    int*   rowptr    = loc + 3 * NND;                   // 3*(NND+1)
    int*   cursor    = rowptr + 3 * (NND + 1) + 64;     // 3*NND (pad for alignment)
    int*   partials  = cursor + 3 * NND;                // 3*512
    int*   sortedsrc = partials + 3 * 512;              // 3*NED
    float* hidden = out;                                // alias d_out

    hipMemsetAsync(stats, 0, 4 * 128 * sizeof(float), stream);
    hipMemsetAsync(deg, 0, 3 * NND * sizeof(int), stream);

    // CSR build for all 3 hops
    k_deg3<<<2048, 256, 0, stream>>>(edges, deg);
    k_scan1<<<3 * NB1, 256, 0, stream>>>(deg, loc, partials);
    k_scan2<<<3, 512, 0, stream>>>(partials);
    k_fin<<<(3 * (NND + 1) + 255) / 256, 256, 0, stream>>>(loc, partials, rowptr, cursor);
    k_bucket3<<<2048, 256, 0, stream>>>(edges, cursor, sortedsrc);

    // ego GEMM (stats slot 0 fused)
    k_gemm<<<1024, 256, 0, stream>>>(bb, comb_w, 0, ego_W, rowptr, 0, stats, 1, xwsA);

    for (int h = 0; h < NHOP; h++) {
        const int* rp = rowptr + h * (NND + 1);
        const int* ss = sortedsrc + (i64)h * NED;
        float* statsB = stats + (h + 1) * 128;
        k_gemm<<<1024, 256, 0, stream>>>(bb, comb_w, h + 1, conv_W + (i64)h * DM * DM,
                                         rp, 1, statsB, 0, xwsB);
        k_gather<<<6144, 256, 0, stream>>>(xwsB, ss, rp, xbuf, statsB);
        k_apply<<<768, 256, 0, stream>>>(xbuf, xwsA, h, stats, statsB, hidden, out);
    }
}

// Round 9
// 1164.016 us; speedup vs baseline: 1.0089x; 1.0089x over previous
//
#include <hip/hip_runtime.h>
#include <hip/hip_bf16.h>

#define NND 100000
#define NED 1200000
#define NHOP 3
#define DM 64
#define EPSV 1e-5f
#define NB1 391    // ceil(NND/256)
#define NPASS 8    // bucket3 dst-range passes
#define DRNG 12500 // NND / NPASS

typedef long long i64;
typedef unsigned short u16;
typedef unsigned int u32;

__device__ __forceinline__ float rlf(float v, int k) {
    return __builtin_bit_cast(float, __builtin_amdgcn_readlane(__builtin_bit_cast(int, v), k));
}
__device__ __forceinline__ float bf2f(u16 b) {
    return __builtin_bit_cast(float, (u32)b << 16);
}
__device__ __forceinline__ u16 f2bf(float f) {
    u32 u = __builtin_bit_cast(u32, f);
    return (u16)((u + 0x7FFFu + ((u >> 16) & 1u)) >> 16);
}
__device__ __forceinline__ float lo_f(u32 w) { return __builtin_bit_cast(float, w << 16); }
__device__ __forceinline__ float hi_f(u32 w) { return __builtin_bit_cast(float, w & 0xFFFF0000u); }

// --- xw = (softmax(comb_w[j]) . bb[1..3]) @ W -> bf16; optional rowptr-scale; optional stats ---
__global__ __launch_bounds__(256) void k_gemm(const float* __restrict__ bb,
                                              const float* __restrict__ comb_w, int j,
                                              const float* __restrict__ W,
                                              const int* __restrict__ rowptr, int scale,
                                              float* __restrict__ stats, int dostats,
                                              u16* __restrict__ xw) {
    const int lane = threadIdx.x & 63;
    float Wcol[DM];
#pragma unroll
    for (int k = 0; k < DM; k++) Wcol[k] = W[k * DM + lane];
    float c0 = comb_w[j * 3 + 0], c1 = comb_w[j * 3 + 1], c2 = comb_w[j * 3 + 2];
    float mx = fmaxf(c0, fmaxf(c1, c2));
    float e0 = expf(c0 - mx), e1 = expf(c1 - mx), e2 = expf(c2 - mx);
    float es = 1.0f / (e0 + e1 + e2);
    const float w0 = e0 * es, w1 = e1 * es, w2 = e2 * es;
    const float* b1 = bb + (i64)1 * NND * DM;
    const float* b2 = bb + (i64)2 * NND * DM;
    const float* b3 = bb + (i64)3 * NND * DM;
    int wave = (int)((blockIdx.x * blockDim.x + threadIdx.x) >> 6);
    int nw = (int)((gridDim.x * blockDim.x) >> 6);
    float s = 0.f, sq = 0.f;
    for (int n = wave; n < NND; n += nw) {
        i64 base = (i64)n * DM + lane;
        float m = w0 * b1[base] + w1 * b2[base] + w2 * b3[base];
        float a0 = 0.f, a1 = 0.f, a2 = 0.f, a3 = 0.f;
#pragma unroll
        for (int k = 0; k < DM; k += 4) {
            a0 = fmaf(rlf(m, k + 0), Wcol[k + 0], a0);
            a1 = fmaf(rlf(m, k + 1), Wcol[k + 1], a1);
            a2 = fmaf(rlf(m, k + 2), Wcol[k + 2], a2);
            a3 = fmaf(rlf(m, k + 3), Wcol[k + 3], a3);
        }
        float r = (a0 + a1) + (a2 + a3);
        if (scale) {
            int rs = rowptr[n], re = rowptr[n + 1];
            r *= rsqrtf((float)(re - rs) + 1.0f);
        }
        xw[base] = f2bf(r);
        s += r; sq += r * r;
    }
    if (dostats) {
        __shared__ float ls[4][DM], lq[4][DM];
        int row = threadIdx.x >> 6;
        ls[row][lane] = s; lq[row][lane] = sq;
        __syncthreads();
        if (row == 0) {
            s  = ls[0][lane] + ls[1][lane] + ls[2][lane] + ls[3][lane];
            sq = lq[0][lane] + lq[1][lane] + lq[2][lane] + lq[3][lane];
            unsafeAtomicAdd(&stats[lane], s);
            unsafeAtomicAdd(&stats[DM + lane], sq);
        }
    }
}

// --- in-degree histogram, all 3 hops in one pass ---
__global__ __launch_bounds__(256) void k_deg3(const int* __restrict__ edges, int* __restrict__ deg) {
    int i = blockIdx.x * blockDim.x + threadIdx.x;
    int stride = gridDim.x * blockDim.x;
    for (int e = i; e < NED; e += stride) {
#pragma unroll
        for (int h = 0; h < NHOP; h++) {
            int d = edges[(i64)h * 2 * NED + NED + e];
            atomicAdd(&deg[h * NND + d], 1);
        }
    }
}

// --- scan level 1 (batched over hops): block-local exclusive scan ---
__global__ __launch_bounds__(256) void k_scan1(const int* __restrict__ deg,
                                               int* __restrict__ loc,
                                               int* __restrict__ partials) {
    int t = threadIdx.x;
    int h = blockIdx.x / NB1;
    int lb = blockIdx.x - h * NB1;
    int n = lb * 256 + t;
    int d = (n < NND) ? deg[h * NND + n] : 0;
    __shared__ int sh[256];
    sh[t] = d;
    __syncthreads();
    for (int o = 1; o < 256; o <<= 1) {
        int v = (t >= o) ? sh[t - o] : 0;
        __syncthreads();
        sh[t] += v;
        __syncthreads();
    }
    if (n < NND) loc[h * NND + n] = sh[t] - d;
    if (t == 255) partials[h * 512 + lb] = sh[255];
}

// --- scan level 2: exclusive scan of block totals per hop ---
__global__ __launch_bounds__(512) void k_scan2(int* __restrict__ partials) {
    int t = threadIdx.x;
    int h = blockIdx.x;
    int d = (t < NB1) ? partials[h * 512 + t] : 0;
    __shared__ int sh[512];
    sh[t] = d;
    __syncthreads();
    for (int o = 1; o < 512; o <<= 1) {
        int v = (t >= o) ? sh[t - o] : 0;
        __syncthreads();
        sh[t] += v;
        __syncthreads();
    }
    if (t < NB1) partials[h * 512 + t] = sh[t] - d;
}

// --- finalize: rowptr (+sentinel) and cursor copy ---
__global__ __launch_bounds__(256) void k_fin(const int* __restrict__ loc,
                                             const int* __restrict__ partials,
                                             int* __restrict__ rowptr,
                                             int* __restrict__ cursor) {
    int i = blockIdx.x * blockDim.x + threadIdx.x;
    if (i >= NHOP * (NND + 1)) return;
    int h = i / (NND + 1);
    int n = i - h * (NND + 1);
    int v;
    if (n == NND) v = NED;
    else v = partials[h * 512 + (n >> 8)] + loc[h * NND + n];
    rowptr[h * (NND + 1) + n] = v;
    if (n < NND) cursor[h * NND + n] = v;
}

// --- bucket all 3 hops, multi-pass by dst range: pass p = blockIdx/256 handles
//     dst in [p*DRNG,(p+1)*DRNG) so writes stay L2-resident (~600KB/hop/pass) ---
__global__ __launch_bounds__(256) void k_bucket3(const int* __restrict__ edges,
                                                 int* __restrict__ cursor,
                                                 int* __restrict__ sortedsrc) {
    int p = blockIdx.x >> 8;                  // 2048 blocks -> 8 passes x 256 blocks
    int lo = p * DRNG, hi = lo + DRNG;
    int i = (blockIdx.x & 255) * blockDim.x + threadIdx.x;
    int stride = 256 * blockDim.x;
    for (int e = i; e < NED; e += stride) {
#pragma unroll
        for (int h = 0; h < NHOP; h++) {
            int d = edges[(i64)h * 2 * NED + NED + e];
            if (d >= lo && d < hi) {
                int s = edges[(i64)h * 2 * NED + e];
                int pos = atomicAdd(&cursor[h * NND + d], 1);
                sortedsrc[(i64)h * NED + pos] = s;
            }
        }
    }
}

// --- gather: 8 edges per wave-load; x[n] = (sum xws[s] + xws[n]) * rsqrt(cnt+1); fused stats ---
__global__ __launch_bounds__(256) void k_gather(const u16* __restrict__ xws,
                                                const int* __restrict__ sorted,
                                                const int* __restrict__ rowptr,
                                                u16* __restrict__ xbuf,
                                                float* __restrict__ stats) {
    const int lane = threadIdx.x & 63;
    const int g = lane >> 3;   // edge slot 0..7
    const int c = lane & 7;    // feature chunk: features c*8 .. c*8+7
    const int wv = threadIdx.x >> 6;
    int wave = (int)((blockIdx.x * blockDim.x + threadIdx.x) >> 6);
    int nw = (int)((gridDim.x * blockDim.x) >> 6);
    float sA[8] = {0,0,0,0,0,0,0,0}, qA[8] = {0,0,0,0,0,0,0,0};
    for (int n = wave; n < NND; n += nw) {
        int start = rowptr[n];
        int cnt = rowptr[n + 1] - start;
        uint4 sv = *(const uint4*)(xws + (i64)n * DM + c * 8);   // self row chunk
        // self term must survive the 8-way group butterfly exactly once -> weight by (g==0)
        float selfw = (g == 0) ? 1.0f : 0.0f;
        float acc[8];
        acc[0] = lo_f(sv.x) * selfw; acc[1] = hi_f(sv.x) * selfw;
        acc[2] = lo_f(sv.y) * selfw; acc[3] = hi_f(sv.y) * selfw;
        acc[4] = lo_f(sv.z) * selfw; acc[5] = hi_f(sv.z) * selfw;
        acc[6] = lo_f(sv.w) * selfw; acc[7] = hi_f(sv.w) * selfw;
        int base = 0;
        while (base < cnt) {
            int take = cnt - base; if (take > 64) take = 64;
            int eidx = start + base + lane;
            if (eidx > NED - 1) eidx = NED - 1;
            int sli = sorted[eidx];
            int nr = (take + 7) >> 3;
            for (int r = 0; r < nr; r += 2) {
                int i0 = r * 8 + g;
                int i1 = i0 + 8;
                int s0 = __shfl(sli, i0);
                int s1 = __shfl(sli, i1 & 63);
                uint4 v0 = *(const uint4*)(xws + (i64)s0 * DM + c * 8);
                uint4 v1 = *(const uint4*)(xws + (i64)s1 * DM + c * 8);
                float m0 = (i0 < take) ? 1.0f : 0.0f;
                float m1 = (i1 < take) ? 1.0f : 0.0f;
                acc[0] = fmaf(lo_f(v0.x), m0, acc[0]); acc[1] = fmaf(hi_f(v0.x), m0, acc[1]);
                acc[2] = fmaf(lo_f(v0.y), m0, acc[2]); acc[3] = fmaf(hi_f(v0.y), m0, acc[3]);
                acc[4] = fmaf(lo_f(v0.z), m0, acc[4]); acc[5] = fmaf(hi_f(v0.z), m0, acc[5]);
                acc[6] = fmaf(lo_f(v0.w), m0, acc[6]); acc[7] = fmaf(hi_f(v0.w), m0, acc[7]);
                acc[0] = fmaf(lo_f(v1.x), m1, acc[0]); acc[1] = fmaf(hi_f(v1.x), m1, acc[1]);
                acc[2] = fmaf(lo_f(v1.y), m1, acc[2]); acc[3] = fmaf(hi_f(v1.y), m1, acc[3]);
                acc[4] = fmaf(lo_f(v1.z), m1, acc[4]); acc[5] = fmaf(hi_f(v1.z), m1, acc[5]);
                acc[6] = fmaf(lo_f(v1.w), m1, acc[6]); acc[7] = fmaf(hi_f(v1.w), m1, acc[7]);
            }
            base += take;
        }
        float dinv = rsqrtf((float)cnt + 1.0f);
#pragma unroll
        for (int i = 0; i < 8; i++) {
            float v = acc[i];
            v += __shfl_xor(v, 8);
            v += __shfl_xor(v, 16);
            v += __shfl_xor(v, 32);
            float x = v * dinv;
            acc[i] = x;
            sA[i] += x; qA[i] += x * x;
        }
        if (g == 0) {
            uint4 o;
            o.x = (u32)f2bf(acc[0]) | ((u32)f2bf(acc[1]) << 16);
            o.y = (u32)f2bf(acc[2]) | ((u32)f2bf(acc[3]) << 16);
            o.z = (u32)f2bf(acc[4]) | ((u32)f2bf(acc[5]) << 16);
            o.w = (u32)f2bf(acc[6]) | ((u32)f2bf(acc[7]) << 16);
            *(uint4*)(xbuf + (i64)n * DM + c * 8) = o;
        }
    }
    __shared__ float red[2][4][DM];
    if (g == 0) {
#pragma unroll
        for (int i = 0; i < 8; i++) {
            red[0][wv][c * 8 + i] = sA[i];
            red[1][wv][c * 8 + i] = qA[i];
        }
    }
    __syncthreads();
    if (threadIdx.x < DM) {
        int f = threadIdx.x;
        float s = red[0][0][f] + red[0][1][f] + red[0][2][f] + red[0][3][f];
        float q = red[1][0][f] + red[1][1][f] + red[1][2][f] + red[1][3][f];
        unsafeAtomicAdd(&stats[f], s);
        unsafeAtomicAdd(&stats[DM + f], q);
    }
}

// --- BN apply + accumulate; mode 0 folds ego BN; mode 2 adds log_softmax ---
__global__ __launch_bounds__(256) void k_apply(const u16* __restrict__ xbuf,
                                               const u16* __restrict__ xwsA, int mode,
                                               const float* __restrict__ statsA,
                                               const float* __restrict__ statsB,
                                               float* __restrict__ hidden,
                                               float* __restrict__ out) {
    const int lane = threadIdx.x & 63;
    float meanB = statsB[lane] * (1.0f / NND);
    float varB = statsB[DM + lane] * (1.0f / NND) - meanB * meanB;
    float invB = rsqrtf(varB + EPSV);
    float meanA = 0.f, invA = 0.f;
    if (mode == 0) {
        meanA = statsA[lane] * (1.0f / NND);
        float varA = statsA[DM + lane] * (1.0f / NND) - meanA * meanA;
        invA = rsqrtf(varA + EPSV);
    }
    int wave = (int)((blockIdx.x * blockDim.x + threadIdx.x) >> 6);
    int nw = (int)((gridDim.x * blockDim.x) >> 6);
    for (int n = wave; n < NND; n += nw) {
        i64 i = (i64)n * DM + lane;
        float bn = (bf2f(xbuf[i]) - meanB) * invB;
        float r = fmaxf(bn, 0.0f);
        if (mode == 0) {
            hidden[i] = (bf2f(xwsA[i]) - meanA) * invA + r;
        } else if (mode == 1) {
            hidden[i] += r;
        } else {
            float h = hidden[i] + r;
            float mx = h;
#pragma unroll
            for (int o = 32; o >= 1; o >>= 1) mx = fmaxf(mx, __shfl_xor(mx, o));
            float e = expf(h - mx);
            float ssum = e;
#pragma unroll
            for (int o = 32; o >= 1; o >>= 1) ssum += __shfl_xor(ssum, o);
            out[i] = h - mx - logf(ssum);
        }
    }
}

extern "C" void kernel_launch(void* const* d_in, const int* in_sizes, int n_in,
                              void* d_out, int out_size, void* d_ws, size_t ws_size,
                              hipStream_t stream) {
    const float* bb     = (const float*)d_in[0];
    const float* comb_w = (const float*)d_in[1];
    const float* ego_W  = (const float*)d_in[2];
    const float* conv_W = (const float*)d_in[4];
    const int*   edges  = (const int*)d_in[6];
    float* out = (float*)d_out;

    const i64 NF = (i64)NND * DM;
    char* ws = (char*)d_ws;
    float* stats    = (float*)ws;                      // 4*128 f (4096B reserved)
    u16*   xwsA     = (u16*)(ws + 4096);               // NF bf16 (ego)
    u16*   xws      = xwsA + NF;                       // NF bf16 (per-hop, reused)
    u16*   xbuf     = xws + NF;                        // NF bf16 (per-hop, reused)
    int*   deg      = (int*)(xbuf + NF);               // 3*NND
    int*   loc      = deg + 3 * NND;                   // 3*NND
    int*   rowptr   = loc + 3 * NND;                   // 3*(NND+1)
    int*   cursor   = rowptr + 3 * (NND + 1) + 64;     // 3*NND (pad for alignment)
    int*   partials = cursor + 3 * NND;                // 3*512
    int*   sortedsrc = partials + 3 * 512;             // 3*NED
    float* hidden = out;                               // alias d_out

    hipMemsetAsync(stats, 0, 4 * 128 * sizeof(float), stream);
    hipMemsetAsync(deg, 0, 3 * NND * sizeof(int), stream);

    // CSR build for all 3 hops (R5-verified path; bucket3 now range-passed)
    k_deg3<<<2048, 256, 0, stream>>>(edges, deg);
    k_scan1<<<3 * NB1, 256, 0, stream>>>(deg, loc, partials);
    k_scan2<<<3, 512, 0, stream>>>(partials);
    k_fin<<<(3 * (NND + 1) + 255) / 256, 256, 0, stream>>>(loc, partials, rowptr, cursor);
    k_bucket3<<<2048, 256, 0, stream>>>(edges, cursor, sortedsrc);

    // ego GEMM (stats slot 0 fused)
    k_gemm<<<1024, 256, 0, stream>>>(bb, comb_w, 0, ego_W, rowptr, 0, stats, 1, xwsA);

    for (int h = 0; h < NHOP; h++) {
        const int* rp = rowptr + h * (NND + 1);
        float* statsB = stats + (h + 1) * 128;
        k_gemm<<<1024, 256, 0, stream>>>(bb, comb_w, h + 1, conv_W + (i64)h * DM * DM,
                                         rp, 1, statsB, 0, xws);
        k_gather<<<6144, 256, 0, stream>>>(xws, sortedsrc + (i64)h * NED, rp, xbuf, statsB);
        k_apply<<<768, 256, 0, stream>>>(xbuf, xwsA, h, stats, statsB, hidden, out);
    }
}